// Round 1
// baseline (5441.784 us; speedup 1.0000x reference)
//
#include <hip/hip_runtime.h>
#include <math.h>

#define N_NODES 100000
#define N_EDGES 3200000
#define D_NODE 22
#define HIDDEN 32

__device__ __forceinline__ float softplus_f(float v) {
    // jax.nn.softplus = logaddexp(v, 0) = max(v,0) + log1p(exp(-|v|))
    return fmaxf(v, 0.0f) + log1pf(expf(-fabsf(v)));
}

// One thread per edge: msg = relu([x_i | x_j | ea] @ W1 + b1) @ W2 + b2
// then atomicAdd into agg[src].
// Weights are read with wave-uniform indices -> compiler emits s_load into
// SGPRs; each MAC is a single v_fmac_f32 v, s, v.
__global__ __launch_bounds__(256) void edge_mlp_kernel(
    const float* __restrict__ x,
    const int*   __restrict__ edge_index,   // [2, E]
    const float* __restrict__ edge_attr,    // [E, 22]
    const float* __restrict__ W1,           // [66, 32] row-major
    const float* __restrict__ b1,           // [32]
    const float* __restrict__ W2,           // [32, 32]
    const float* __restrict__ b2,           // [32]
    float*       __restrict__ agg)          // [N, 32]
{
    int e = blockIdx.x * blockDim.x + threadIdx.x;
    if (e >= N_EDGES) return;

    const int i = edge_index[e];            // src (aggregation target)
    const int j = edge_index[N_EDGES + e];  // dst

    const float* __restrict__ xi = x + (size_t)i * D_NODE;
    const float* __restrict__ xj = x + (size_t)j * D_NODE;
    const float* __restrict__ ep = edge_attr + (size_t)e * D_NODE;

    float hid[HIDDEN];
#pragma unroll
    for (int h = 0; h < HIDDEN; ++h) hid[h] = b1[h];

    // layer 1: three concatenated segments of the 66-dim input
#pragma unroll
    for (int k = 0; k < D_NODE; ++k) {
        const float t = xi[k];
#pragma unroll
        for (int h = 0; h < HIDDEN; ++h)
            hid[h] = fmaf(t, W1[k * HIDDEN + h], hid[h]);
    }
#pragma unroll
    for (int k = 0; k < D_NODE; ++k) {
        const float t = xj[k];
#pragma unroll
        for (int h = 0; h < HIDDEN; ++h)
            hid[h] = fmaf(t, W1[(D_NODE + k) * HIDDEN + h], hid[h]);
    }
#pragma unroll
    for (int k = 0; k < D_NODE; ++k) {
        const float t = ep[k];
#pragma unroll
        for (int h = 0; h < HIDDEN; ++h)
            hid[h] = fmaf(t, W1[(2 * D_NODE + k) * HIDDEN + h], hid[h]);
    }

    // ReLU
#pragma unroll
    for (int h = 0; h < HIDDEN; ++h) hid[h] = fmaxf(hid[h], 0.0f);

    // layer 2
    float msg[HIDDEN];
#pragma unroll
    for (int o = 0; o < HIDDEN; ++o) msg[o] = b2[o];
#pragma unroll
    for (int k = 0; k < HIDDEN; ++k) {
        const float t = hid[k];
#pragma unroll
        for (int o = 0; o < HIDDEN; ++o)
            msg[o] = fmaf(t, W2[k * HIDDEN + o], msg[o]);
    }

    // scatter-add into agg[src]
    float* __restrict__ ap = agg + (size_t)i * HIDDEN;
#pragma unroll
    for (int o = 0; o < HIDDEN; ++o)
        atomicAdd(ap + o, msg[o]);
}

// One thread per node: h = [x | agg]; out = softplus(h @ W + b) for 3 heads.
__global__ __launch_bounds__(256) void node_head_kernel(
    const float* __restrict__ x,     // [N, 22]
    const float* __restrict__ agg,   // [N, 32]
    const float* __restrict__ Wmu,   // [54]
    const float* __restrict__ bmu,
    const float* __restrict__ Wsig,
    const float* __restrict__ bsig,
    const float* __restrict__ Wconc,
    const float* __restrict__ bconc,
    float*       __restrict__ out)   // [3*N] : mu | sigma | alpha
{
    int n = blockIdx.x * blockDim.x + threadIdx.x;
    if (n >= N_NODES) return;

    float mu = bmu[0], sg = bsig[0], al = bconc[0];

    const float* __restrict__ xp = x + (size_t)n * D_NODE;
#pragma unroll
    for (int k = 0; k < D_NODE; ++k) {
        const float t = xp[k];
        mu = fmaf(t, Wmu[k], mu);
        sg = fmaf(t, Wsig[k], sg);
        al = fmaf(t, Wconc[k], al);
    }
    const float* __restrict__ ap = agg + (size_t)n * HIDDEN;
#pragma unroll
    for (int k = 0; k < HIDDEN; ++k) {
        const float t = ap[k];
        mu = fmaf(t, Wmu[D_NODE + k], mu);
        sg = fmaf(t, Wsig[D_NODE + k], sg);
        al = fmaf(t, Wconc[D_NODE + k], al);
    }

    out[n] = softplus_f(mu);
    out[N_NODES + n] = softplus_f(sg);
    out[2 * N_NODES + n] = softplus_f(al);
}

extern "C" void kernel_launch(void* const* d_in, const int* in_sizes, int n_in,
                              void* d_out, int out_size, void* d_ws, size_t ws_size,
                              hipStream_t stream) {
    const float* x     = (const float*)d_in[0];
    const int*   ei    = (const int*)  d_in[1];
    const float* ea    = (const float*)d_in[2];
    const float* W1    = (const float*)d_in[3];
    const float* b1    = (const float*)d_in[4];
    const float* W2    = (const float*)d_in[5];
    const float* b2    = (const float*)d_in[6];
    const float* Wmu   = (const float*)d_in[7];
    const float* bmu   = (const float*)d_in[8];
    const float* Wsig  = (const float*)d_in[9];
    const float* bsig  = (const float*)d_in[10];
    const float* Wconc = (const float*)d_in[11];
    const float* bconc = (const float*)d_in[12];

    float* out = (float*)d_out;
    float* agg = (float*)d_ws;   // [N_NODES, 32] fp32 accumulator

    hipMemsetAsync(agg, 0, (size_t)N_NODES * HIDDEN * sizeof(float), stream);

    edge_mlp_kernel<<<(N_EDGES + 255) / 256, 256, 0, stream>>>(
        x, ei, ea, W1, b1, W2, b2, agg);

    node_head_kernel<<<(N_NODES + 255) / 256, 256, 0, stream>>>(
        x, agg, Wmu, bmu, Wsig, bsig, Wconc, bconc, out);
}

// Round 2
// 2373.673 us; speedup vs baseline: 2.2926x; 2.2926x over previous
//
#include <hip/hip_runtime.h>
#include <math.h>

#define N_NODES 100000
#define N_EDGES 3200000
#define D_NODE 22
#define HIDDEN 32

// scan geometry: 98 blocks * 1024 elements = 100352 >= N_NODES
#define SCAN_ELEMS 1024
#define SCAN_NB    98
#define N_PAD      (SCAN_NB * SCAN_ELEMS)

__device__ __forceinline__ float softplus_f(float v) {
    // jax.nn.softplus = max(v,0) + log1p(exp(-|v|))
    return fmaxf(v, 0.0f) + log1pf(expf(-fabsf(v)));
}

// ---- CSR build ------------------------------------------------------------

__global__ __launch_bounds__(256) void count_kernel(
    const int* __restrict__ ei, int* __restrict__ counts)
{
    int e = blockIdx.x * blockDim.x + threadIdx.x;
    if (e < N_EDGES) atomicAdd(&counts[ei[e]], 1);
}

// exclusive scan, stage 1: per-block (1024 elems = 4/thread), write partial
// exclusive offsets + block totals
__global__ __launch_bounds__(256) void scan_part(
    const int* __restrict__ counts, int* __restrict__ offsets,
    int* __restrict__ bsums)
{
    __shared__ int lds[256];
    const int tid = threadIdx.x;
    const int base = blockIdx.x * SCAN_ELEMS + tid * 4;

    int v0 = (base + 0 < N_NODES) ? counts[base + 0] : 0;
    int v1 = (base + 1 < N_NODES) ? counts[base + 1] : 0;
    int v2 = (base + 2 < N_NODES) ? counts[base + 2] : 0;
    int v3 = (base + 3 < N_NODES) ? counts[base + 3] : 0;
    const int s = v0 + v1 + v2 + v3;

    lds[tid] = s;
    __syncthreads();
    // inclusive Hillis-Steele scan over 256 thread sums
    for (int off = 1; off < 256; off <<= 1) {
        int t = (tid >= off) ? lds[tid - off] : 0;
        __syncthreads();
        lds[tid] += t;
        __syncthreads();
    }
    const int excl = lds[tid] - s;   // exclusive prefix of this thread

    int o0 = excl;
    int o1 = o0 + v0;
    int o2 = o1 + v1;
    int o3 = o2 + v2;
    offsets[base + 0] = o0;
    offsets[base + 1] = o1;
    offsets[base + 2] = o2;
    offsets[base + 3] = o3;

    if (tid == 0) bsums[blockIdx.x] = lds[255];
}

// stage 2: single block exclusive-scans the 98 block totals in place
__global__ __launch_bounds__(128) void scan_sums(int* __restrict__ bsums)
{
    __shared__ int lds[128];
    const int tid = threadIdx.x;
    int v = (tid < SCAN_NB) ? bsums[tid] : 0;
    lds[tid] = v;
    __syncthreads();
    for (int off = 1; off < 128; off <<= 1) {
        int t = (tid >= off) ? lds[tid - off] : 0;
        __syncthreads();
        lds[tid] += t;
        __syncthreads();
    }
    if (tid < SCAN_NB) bsums[tid] = lds[tid] - v;  // exclusive
}

// stage 3: add block offsets
__global__ __launch_bounds__(256) void scan_add(
    int* __restrict__ offsets, const int* __restrict__ bsums)
{
    const int add = bsums[blockIdx.x];
    const int base = blockIdx.x * SCAN_ELEMS + threadIdx.x * 4;
    offsets[base + 0] += add;
    offsets[base + 1] += add;
    offsets[base + 2] += add;
    offsets[base + 3] += add;
}

// fill: slot = offsets[src]++, edge_list[slot] = e.
// After this kernel offsets[n] == end_n; start_n = end_n - counts[n].
__global__ __launch_bounds__(256) void fill_kernel(
    const int* __restrict__ ei, int* __restrict__ offsets,
    int* __restrict__ edge_list)
{
    int e = blockIdx.x * blockDim.x + threadIdx.x;
    if (e < N_EDGES) {
        int pos = atomicAdd(&offsets[ei[e]], 1);
        edge_list[pos] = e;
    }
}

// ---- fused node kernel: per-node edge-MLP recompute + register agg + heads
__global__ __launch_bounds__(256) void node_kernel(
    const float* __restrict__ x,
    const int*   __restrict__ edge_index,   // [2, E]
    const float* __restrict__ edge_attr,    // [E, 22]
    const int*   __restrict__ counts,
    const int*   __restrict__ offsets,      // post-fill: end positions
    const int*   __restrict__ edge_list,
    const float* __restrict__ W1,           // [66, 32]
    const float* __restrict__ b1,           // [32]
    const float* __restrict__ W2,           // [32, 32]
    const float* __restrict__ b2,           // [32]
    const float* __restrict__ Wmu,  const float* __restrict__ bmu,
    const float* __restrict__ Wsig, const float* __restrict__ bsig,
    const float* __restrict__ Wconc,const float* __restrict__ bconc,
    float*       __restrict__ out)          // mu | sigma | alpha
{
    const int n = blockIdx.x * blockDim.x + threadIdx.x;
    if (n >= N_NODES) return;

    const int deg = counts[n];
    const int end = offsets[n];
    const int start = end - deg;

    // x_i stays in registers for all edges of this node
    float xi[D_NODE];
    const float* __restrict__ xp = x + (size_t)n * D_NODE;
#pragma unroll
    for (int k = 0; k < D_NODE; ++k) xi[k] = xp[k];

    float acc[HIDDEN];
#pragma unroll
    for (int o = 0; o < HIDDEN; ++o) acc[o] = 0.0f;

    for (int p = start; p < end; ++p) {
        const int e = edge_list[p];
        const int j = edge_index[N_EDGES + e];
        const float* __restrict__ xj = x + (size_t)j * D_NODE;
        const float* __restrict__ ep = edge_attr + (size_t)e * D_NODE;

        float hid[HIDDEN];
#pragma unroll
        for (int h = 0; h < HIDDEN; ++h) hid[h] = b1[h];

#pragma unroll
        for (int k = 0; k < D_NODE; ++k) {
            const float t = xi[k];
#pragma unroll
            for (int h = 0; h < HIDDEN; ++h)
                hid[h] = fmaf(t, W1[k * HIDDEN + h], hid[h]);
        }
#pragma unroll
        for (int k = 0; k < D_NODE; ++k) {
            const float t = xj[k];
#pragma unroll
            for (int h = 0; h < HIDDEN; ++h)
                hid[h] = fmaf(t, W1[(D_NODE + k) * HIDDEN + h], hid[h]);
        }
#pragma unroll
        for (int k = 0; k < D_NODE; ++k) {
            const float t = ep[k];
#pragma unroll
            for (int h = 0; h < HIDDEN; ++h)
                hid[h] = fmaf(t, W1[(2 * D_NODE + k) * HIDDEN + h], hid[h]);
        }

#pragma unroll
        for (int h = 0; h < HIDDEN; ++h) hid[h] = fmaxf(hid[h], 0.0f);

        // layer 2 accumulated straight into acc (b2 folded in after loop)
#pragma unroll
        for (int k = 0; k < HIDDEN; ++k) {
            const float t = hid[k];
#pragma unroll
            for (int o = 0; o < HIDDEN; ++o)
                acc[o] = fmaf(t, W2[k * HIDDEN + o], acc[o]);
        }
    }

    // fold deg * b2 into the aggregate (segment_sum of per-edge +b2)
    const float degf = (float)deg;
#pragma unroll
    for (int o = 0; o < HIDDEN; ++o)
        acc[o] = fmaf(degf, b2[o], acc[o]);

    // heads: h = [x_i | acc] (54) -> 3 dots + softplus
    float mu = bmu[0], sg = bsig[0], al = bconc[0];
#pragma unroll
    for (int k = 0; k < D_NODE; ++k) {
        const float t = xi[k];
        mu = fmaf(t, Wmu[k],   mu);
        sg = fmaf(t, Wsig[k],  sg);
        al = fmaf(t, Wconc[k], al);
    }
#pragma unroll
    for (int k = 0; k < HIDDEN; ++k) {
        const float t = acc[k];
        mu = fmaf(t, Wmu[D_NODE + k],   mu);
        sg = fmaf(t, Wsig[D_NODE + k],  sg);
        al = fmaf(t, Wconc[D_NODE + k], al);
    }

    out[n]               = softplus_f(mu);
    out[N_NODES + n]     = softplus_f(sg);
    out[2 * N_NODES + n] = softplus_f(al);
}

// ---- launch ---------------------------------------------------------------

extern "C" void kernel_launch(void* const* d_in, const int* in_sizes, int n_in,
                              void* d_out, int out_size, void* d_ws, size_t ws_size,
                              hipStream_t stream) {
    const float* x     = (const float*)d_in[0];
    const int*   ei    = (const int*)  d_in[1];
    const float* ea    = (const float*)d_in[2];
    const float* W1    = (const float*)d_in[3];
    const float* b1    = (const float*)d_in[4];
    const float* W2    = (const float*)d_in[5];
    const float* b2    = (const float*)d_in[6];
    const float* Wmu   = (const float*)d_in[7];
    const float* bmu   = (const float*)d_in[8];
    const float* Wsig  = (const float*)d_in[9];
    const float* bsig  = (const float*)d_in[10];
    const float* Wconc = (const float*)d_in[11];
    const float* bconc = (const float*)d_in[12];

    float* out = (float*)d_out;

    // workspace layout (ints): counts[N_PAD] | offsets[N_PAD] | bsums[128] | edge_list[E]
    int* counts    = (int*)d_ws;
    int* offsets   = counts + N_PAD;
    int* bsums     = offsets + N_PAD;
    int* edge_list = bsums + 128;

    hipMemsetAsync(counts, 0, N_PAD * sizeof(int), stream);

    count_kernel<<<(N_EDGES + 255) / 256, 256, 0, stream>>>(ei, counts);
    scan_part<<<SCAN_NB, 256, 0, stream>>>(counts, offsets, bsums);
    scan_sums<<<1, 128, 0, stream>>>(bsums);
    scan_add<<<SCAN_NB, 256, 0, stream>>>(offsets, bsums);
    fill_kernel<<<(N_EDGES + 255) / 256, 256, 0, stream>>>(ei, offsets, edge_list);

    node_kernel<<<(N_NODES + 255) / 256, 256, 0, stream>>>(
        x, ei, ea, counts, offsets, edge_list,
        W1, b1, W2, b2, Wmu, bmu, Wsig, bsig, Wconc, bconc, out);
}

// Round 3
// 522.531 us; speedup vs baseline: 10.4143x; 4.5426x over previous
//
#include <hip/hip_runtime.h>
#include <math.h>

#define N_NODES 100000
#define N_EDGES 3200000
#define D_NODE 22
#define HIDDEN 32

// scan geometry: 98 blocks * 1024 elements = 100352 >= N_NODES
#define SCAN_ELEMS 1024
#define SCAN_NB    98
#define N_PAD      (SCAN_NB * SCAN_ELEMS)

#define EDGE_NB    (N_EDGES / 256)   // 12500 exact

__device__ __forceinline__ float softplus_f(float v) {
    return fmaxf(v, 0.0f) + log1pf(expf(-fabsf(v)));
}

// ---- CSR build ------------------------------------------------------------

// count AND record each edge's within-node rank (fill becomes atomic-free)
__global__ __launch_bounds__(256) void count_rank_kernel(
    const int* __restrict__ ei, int* __restrict__ counts,
    int* __restrict__ rank)
{
    int e = blockIdx.x * blockDim.x + threadIdx.x;
    if (e < N_EDGES) rank[e] = atomicAdd(&counts[ei[e]], 1);
}

__global__ __launch_bounds__(256) void scan_part(
    const int* __restrict__ counts, int* __restrict__ offsets,
    int* __restrict__ bsums)
{
    __shared__ int lds[256];
    const int tid = threadIdx.x;
    const int base = blockIdx.x * SCAN_ELEMS + tid * 4;

    int v0 = (base + 0 < N_NODES) ? counts[base + 0] : 0;
    int v1 = (base + 1 < N_NODES) ? counts[base + 1] : 0;
    int v2 = (base + 2 < N_NODES) ? counts[base + 2] : 0;
    int v3 = (base + 3 < N_NODES) ? counts[base + 3] : 0;
    const int s = v0 + v1 + v2 + v3;

    lds[tid] = s;
    __syncthreads();
    for (int off = 1; off < 256; off <<= 1) {
        int t = (tid >= off) ? lds[tid - off] : 0;
        __syncthreads();
        lds[tid] += t;
        __syncthreads();
    }
    const int excl = lds[tid] - s;

    offsets[base + 0] = excl;
    offsets[base + 1] = excl + v0;
    offsets[base + 2] = excl + v0 + v1;
    offsets[base + 3] = excl + v0 + v1 + v2;

    if (tid == 0) bsums[blockIdx.x] = lds[255];
}

__global__ __launch_bounds__(128) void scan_sums(int* __restrict__ bsums)
{
    __shared__ int lds[128];
    const int tid = threadIdx.x;
    int v = (tid < SCAN_NB) ? bsums[tid] : 0;
    lds[tid] = v;
    __syncthreads();
    for (int off = 1; off < 128; off <<= 1) {
        int t = (tid >= off) ? lds[tid - off] : 0;
        __syncthreads();
        lds[tid] += t;
        __syncthreads();
    }
    if (tid < SCAN_NB) bsums[tid] = lds[tid] - v;
}

__global__ __launch_bounds__(256) void scan_add(
    int* __restrict__ offsets, const int* __restrict__ bsums)
{
    const int add = bsums[blockIdx.x];
    const int base = blockIdx.x * SCAN_ELEMS + threadIdx.x * 4;
    offsets[base + 0] += add;
    offsets[base + 1] += add;
    offsets[base + 2] += add;
    offsets[base + 3] += add;
}

// atomic-free fill: pos = start[src] + rank[e]
__global__ __launch_bounds__(256) void fill_kernel(
    const int* __restrict__ ei, const int* __restrict__ offsets,
    const int* __restrict__ rank, int* __restrict__ edge_list)
{
    int e = blockIdx.x * blockDim.x + threadIdx.x;
    if (e < N_EDGES)
        edge_list[offsets[ei[e]] + rank[e]] = e;
}

// ---- edge-parallel MLP + block-level segmented reduction ------------------
// One lane per CSR position. 256 edges/block. Edges globally sorted by src,
// so interior segments of a block are COMPLETE nodes -> plain coalesced
// store; only the first/last segment of each block needs atomicAdd.
__global__ __launch_bounds__(256) void edge_mlp_reduce(
    const float* __restrict__ x,
    const int*   __restrict__ edge_index,   // [2, E]
    const float* __restrict__ edge_attr,    // [E, 22]
    const int*   __restrict__ edge_list,    // CSR-ordered edge ids
    const float* __restrict__ W1,           // [66, 32]
    const float* __restrict__ b1,           // [32]
    const float* __restrict__ W2,           // [32, 32]
    const float* __restrict__ b2,           // [32]
    float*       __restrict__ agg)          // [N, 32]
{
    __shared__ float lmsg[256][33];   // +1 pad: 2-way conflicts only
    __shared__ int   lsrc[256];
    __shared__ int   lstart[257];
    __shared__ unsigned long long lmask[4];

    const int tid = threadIdx.x;
    const int p = blockIdx.x * 256 + tid;

    const int e   = edge_list[p];
    const int src = edge_index[e];
    const int j   = edge_index[N_EDGES + e];

    const float* __restrict__ xi = x + (size_t)src * D_NODE;
    const float* __restrict__ xj = x + (size_t)j   * D_NODE;
    const float* __restrict__ ep = edge_attr + (size_t)e * D_NODE;

    // ---- per-edge MLP (weights stream through SGPRs: wave-uniform) ----
    float hid[HIDDEN];
#pragma unroll
    for (int h = 0; h < HIDDEN; ++h) hid[h] = b1[h];

#pragma unroll
    for (int k = 0; k < D_NODE; ++k) {
        const float t = xi[k];
#pragma unroll
        for (int h = 0; h < HIDDEN; ++h)
            hid[h] = fmaf(t, W1[k * HIDDEN + h], hid[h]);
    }
#pragma unroll
    for (int k = 0; k < D_NODE; ++k) {
        const float t = xj[k];
#pragma unroll
        for (int h = 0; h < HIDDEN; ++h)
            hid[h] = fmaf(t, W1[(D_NODE + k) * HIDDEN + h], hid[h]);
    }
#pragma unroll
    for (int k = 0; k < D_NODE; ++k) {
        const float t = ep[k];
#pragma unroll
        for (int h = 0; h < HIDDEN; ++h)
            hid[h] = fmaf(t, W1[(2 * D_NODE + k) * HIDDEN + h], hid[h]);
    }

#pragma unroll
    for (int h = 0; h < HIDDEN; ++h) hid[h] = fmaxf(hid[h], 0.0f);

    float msg[HIDDEN];
#pragma unroll
    for (int o = 0; o < HIDDEN; ++o) msg[o] = b2[o];
#pragma unroll
    for (int k = 0; k < HIDDEN; ++k) {
        const float t = hid[k];
#pragma unroll
        for (int o = 0; o < HIDDEN; ++o)
            msg[o] = fmaf(t, W2[k * HIDDEN + o], msg[o]);
    }

    lsrc[tid] = src;
#pragma unroll
    for (int o = 0; o < HIDDEN; ++o) lmsg[tid][o] = msg[o];
    __syncthreads();

    // ---- segment boundaries ----
    const bool head = (tid == 0) || (lsrc[tid] != lsrc[tid - 1]);
    const unsigned long long m = __ballot(head ? 1 : 0);
    const int wv = tid >> 6, lane = tid & 63;
    if (lane == 0) lmask[wv] = m;
    __syncthreads();

    const int nseg = __popcll(lmask[0]) + __popcll(lmask[1]) +
                     __popcll(lmask[2]) + __popcll(lmask[3]);
    if (head) {
        int sid = 0;
        for (int w = 0; w < 4; ++w)
            if (w < wv) sid += __popcll(lmask[w]);
        const unsigned long long below =
            (lane == 0) ? 0ULL : (lmask[wv] & ((1ULL << lane) - 1ULL));
        sid += __popcll(below);
        lstart[sid] = tid;
    }
    if (tid == 0) lstart[nseg] = 256;
    __syncthreads();

    // ---- per-(segment, channel) sums ----
    for (int item = tid; item < nseg * HIDDEN; item += 256) {
        const int s = item >> 5;
        const int c = item & 31;
        const int st = lstart[s];
        const int en = lstart[s + 1];
        float sum = 0.0f;
        for (int r = st; r < en; ++r) sum += lmsg[r][c];
        const int node = lsrc[st];
        float* dst = agg + (size_t)node * HIDDEN + c;
        if (s == 0 || s == nseg - 1) atomicAdd(dst, sum);  // may span blocks
        else *dst = sum;                                   // complete node
    }
}

// ---- heads ---------------------------------------------------------------
__global__ __launch_bounds__(256) void node_head_kernel(
    const float* __restrict__ x,
    const float* __restrict__ agg,
    const float* __restrict__ Wmu,  const float* __restrict__ bmu,
    const float* __restrict__ Wsig, const float* __restrict__ bsig,
    const float* __restrict__ Wconc,const float* __restrict__ bconc,
    float*       __restrict__ out)
{
    int n = blockIdx.x * blockDim.x + threadIdx.x;
    if (n >= N_NODES) return;

    float mu = bmu[0], sg = bsig[0], al = bconc[0];

    const float* __restrict__ xp = x + (size_t)n * D_NODE;
#pragma unroll
    for (int k = 0; k < D_NODE; ++k) {
        const float t = xp[k];
        mu = fmaf(t, Wmu[k],   mu);
        sg = fmaf(t, Wsig[k],  sg);
        al = fmaf(t, Wconc[k], al);
    }
    const float* __restrict__ ap = agg + (size_t)n * HIDDEN;
#pragma unroll
    for (int k = 0; k < HIDDEN; ++k) {
        const float t = ap[k];
        mu = fmaf(t, Wmu[D_NODE + k],   mu);
        sg = fmaf(t, Wsig[D_NODE + k],  sg);
        al = fmaf(t, Wconc[D_NODE + k], al);
    }

    out[n]               = softplus_f(mu);
    out[N_NODES + n]     = softplus_f(sg);
    out[2 * N_NODES + n] = softplus_f(al);
}

// ---- launch ---------------------------------------------------------------

extern "C" void kernel_launch(void* const* d_in, const int* in_sizes, int n_in,
                              void* d_out, int out_size, void* d_ws, size_t ws_size,
                              hipStream_t stream) {
    const float* x     = (const float*)d_in[0];
    const int*   ei    = (const int*)  d_in[1];
    const float* ea    = (const float*)d_in[2];
    const float* W1    = (const float*)d_in[3];
    const float* b1    = (const float*)d_in[4];
    const float* W2    = (const float*)d_in[5];
    const float* b2    = (const float*)d_in[6];
    const float* Wmu   = (const float*)d_in[7];
    const float* bmu   = (const float*)d_in[8];
    const float* Wsig  = (const float*)d_in[9];
    const float* bsig  = (const float*)d_in[10];
    const float* Wconc = (const float*)d_in[11];
    const float* bconc = (const float*)d_in[12];

    float* out = (float*)d_out;

    // ws layout (4B words):
    //   counts[N_PAD] | offsets[N_PAD] | bsums[128] | edge_list[E] |
    //   region2[E]  (rank during CSR build, then reused as agg[N*32]=E words)
    int* counts    = (int*)d_ws;
    int* offsets   = counts + N_PAD;
    int* bsums     = offsets + N_PAD;
    int* edge_list = bsums + 128;
    int* rank      = edge_list + N_EDGES;     // overlaid with agg
    float* agg     = (float*)rank;            // N_NODES*32 == N_EDGES words

    hipMemsetAsync(counts, 0, N_PAD * sizeof(int), stream);

    count_rank_kernel<<<EDGE_NB, 256, 0, stream>>>(ei, counts, rank);
    scan_part<<<SCAN_NB, 256, 0, stream>>>(counts, offsets, bsums);
    scan_sums<<<1, 128, 0, stream>>>(bsums);
    scan_add<<<SCAN_NB, 256, 0, stream>>>(offsets, bsums);
    fill_kernel<<<EDGE_NB, 256, 0, stream>>>(ei, offsets, rank, edge_list);

    // rank is dead now; zero the same region as agg
    hipMemsetAsync(agg, 0, (size_t)N_NODES * HIDDEN * sizeof(float), stream);

    edge_mlp_reduce<<<EDGE_NB, 256, 0, stream>>>(
        x, ei, ea, edge_list, W1, b1, W2, b2, agg);

    node_head_kernel<<<(N_NODES + 255) / 256, 256, 0, stream>>>(
        x, agg, Wmu, bmu, Wsig, bsig, Wconc, bconc, out);
}